// Round 3
// baseline (263.390 us; speedup 1.0000x reference)
//
#include <hip/hip_runtime.h>
#include <math.h>

// Problem constants (B=8, P=64, V=32, N_TH1=30 -> D=1626)
#define NBP 512          // B*P
#define VV 32
#define DD 1626

// Output layout (flat float32, concatenated in return order)
#define O_POINTS 0                         // (8,64*1626,3)  = 2497536
#define O_DIRH   2497536                   // (8,64,1626,4)  = 3330048
#define O_OVER   5827584                   // (8,64,1)       = 512
#define O_RETR   5828096                   // (8,64,1)       = 512
#define O_MEAN   5828608                   // (8,64,3)       = 1536
#define O_LOCAL  5830144                   // (8,64,32,3)    = 49152

#define L10_2 0.3010299956639812f    // log10(2)
#define L2_10 3.321928094887362f     // log2(10)
#define LH_MIN -66.43856189774725f   // log2(1e-20)

__device__ __forceinline__ float fexp2(float x) {
  return __builtin_amdgcn_exp2f(x);    // raw v_exp_f32
}

// inline direction via hardware v_sin/v_cos
__device__ __forceinline__ void make_dir_fast(int d, float& x, float& y, float& z) {
  if (d < 1624) {
    const int i1 = d / 58 + 1;        // 1..28
    const int i2 = d - (i1 - 1) * 58; // 0..57
    const float STEP = 0.10833078115826873f;        // pi/29
    const float th1 = -1.5707963267948966f + (float)i1 * STEP;
    const float th2 = -3.14159265358979323846f + (float)i2 * STEP;
    const float s1 = __sinf(th1);
    const float c1 = __cosf(th1);
    const float s2 = __sinf(th2);
    const float c2 = __cosf(th2);
    x = c1 * c2; y = c1 * s2; z = s1;
  } else if (d == 1624) {             // pole th1=-pi/2 (numpy f64->f32 values)
    x = -6.123234e-17f; y = -7.49880e-33f; z = -1.0f;
  } else {                            // pole th1=+pi/2
    x = -6.123234e-17f; y = -7.49880e-33f; z = 1.0f;
  }
}

// z-chunk: identical expression/order to the passing round-1/2 kernels
#define ZCHUNK(X, Y, Z, z0, z1, z2, z3)                              \
  z0 = fmaxf(fmaf((X).x, dx, fmaf((Y).x, dy, (Z).x * dz)), 0.f);     \
  z1 = fmaxf(fmaf((X).y, dx, fmaf((Y).y, dy, (Z).y * dz)), 0.f);     \
  z2 = fmaxf(fmaf((X).z, dx, fmaf((Y).z, dy, (Z).z * dz)), 0.f);     \
  z3 = fmaxf(fmaf((X).w, dx, fmaf((Y).w, dy, (Z).w * dz)), 0.f);

// pass-1 chunk: LDS read + running 4-lane max
#define P1CHUNK(j)                                                   \
  { const float4 X = lvx4[j], Y = lvy4[j], Z = lvz4[j];              \
    float z0, z1, z2, z3; ZCHUNK(X, Y, Z, z0, z1, z2, z3)            \
    zm0 = fmaxf(zm0, z0); zm1 = fmaxf(zm1, z1);                      \
    zm2 = fmaxf(zm2, z2); zm3 = fmaxf(zm3, z3); }

// pass-2 chunk: ONE LDS read serves both z-recompute and the fused dhdx FMAs
// w2 = 2^(pm1*log2(z)+A); s += w2*z; a += w2*lv
#define P2CHUNK(j)                                                   \
  { const float4 X = lvx4[j], Y = lvy4[j], Z = lvz4[j];              \
    float z0, z1, z2, z3; ZCHUNK(X, Y, Z, z0, z1, z2, z3)            \
    float w0 = fexp2(fmaf(pm1, __log2f(z0), A));                     \
    float w1 = fexp2(fmaf(pm1, __log2f(z1), A));                     \
    float w2 = fexp2(fmaf(pm1, __log2f(z2), A));                     \
    float w3 = fexp2(fmaf(pm1, __log2f(z3), A));                     \
    s0 += w0 * z0;  s1 += w1 * z1;                                   \
    s2 += w2 * z2;  s3 += w3 * z3;                                   \
    ax = fmaf(w0, (X).x, fmaf(w1, (X).y, fmaf(w2, (X).z, fmaf(w3, (X).w, ax)))); \
    ay = fmaf(w0, (Y).x, fmaf(w1, (Y).y, fmaf(w2, (Y).z, fmaf(w3, (Y).w, ay)))); \
    az = fmaf(w0, (Z).x, fmaf(w1, (Z).y, fmaf(w2, (Z).z, fmaf(w3, (Z).w, az)))); }

// No w[] array -> true live demand ~50 VGPR. Cap at 64 for 8 waves/SIMD.
__global__ __launch_bounds__(256, 8) void spt_kernel(
    const float* __restrict__ vertices,
    const float* __restrict__ smooth,
    float* __restrict__ out)
{
  const int bp  = blockIdx.x;   // 0..511
  const int q   = blockIdx.y;   // 0..3 direction quarter
  const int tid = threadIdx.x;

  __shared__ __align__(16) float slvx[VV];
  __shared__ __align__(16) float slvy[VV];
  __shared__ __align__(16) float slvz[VV];

  // quarter start/count: {407,407,406,406} starting at {0,407,814,1220}
  const int dstart = q * 406 + (q < 2 ? q : 2);
  const int dcount = (q < 2) ? 407 : 406;

  // ---- wave-redundant mean via shuffle; lv -> LDS; ONE barrier ----
  const int v = tid & 31;
  const float* vp = vertices + bp * (VV * 3) + v * 3;
  const float vx = vp[0], vy = vp[1], vz = vp[2];
  float sx = vx, sy = vy, sz = vz;
#pragma unroll
  for (int m = 16; m >= 1; m >>= 1) {
    sx += __shfl_xor(sx, m);
    sy += __shfl_xor(sy, m);
    sz += __shfl_xor(sz, m);
  }
  const float mx = sx * (1.0f / 32.0f);
  const float my = sy * (1.0f / 32.0f);
  const float mz = sz * (1.0f / 32.0f);
  if (tid < VV) {
    slvx[tid] = vx - mx;
    slvy[tid] = vy - my;
    slvz[tid] = vz - mz;
  }
  __syncthreads();

  // ---- side outputs (once, by quarter 3) ----
  if (q == 3) {
    if (tid < VV * 3) {
      const int vv = tid / 3, c = tid - vv * 3;
      const float val = (c == 0) ? slvx[vv] : ((c == 1) ? slvy[vv] : slvz[vv]);
      out[O_LOCAL + bp * (VV * 3) + tid] = val;
    }
    if (tid == 96) {
      out[O_MEAN + bp * 3 + 0] = mx;
      out[O_MEAN + bp * 3 + 1] = my;
      out[O_MEAN + bp * 3 + 2] = mz;
      out[O_OVER + bp] = 0.f;
      out[O_RETR + bp] = 0.f;
    }
  }

  const float p     = smooth[bp];
  const float inv_p = 1.0f / p;
  const float pm1   = p - 1.0f;
  const float plt   = p * L10_2;

  const float4* lvx4 = (const float4*)slvx;
  const float4* lvy4 = (const float4*)slvy;
  const float4* lvz4 = (const float4*)slvz;

#pragma unroll 2
  for (int rep = 0; rep < 2; ++rep) {
    const int idx = rep * 256 + tid;
    if (idx >= dcount) break;          // rep 0 never breaks (dcount >= 406)
    const int d = dstart + idx;
    float dx, dy, dz;
    make_dir_fast(d, dx, dy, dz);

    // ---- pass 1: zmax ----
    float zm0 = 0.f, zm1 = 0.f, zm2 = 0.f, zm3 = 0.f;
    P1CHUNK(0) P1CHUNK(1) P1CHUNK(2) P1CHUNK(3)
    P1CHUNK(4) P1CHUNK(5) P1CHUNK(6) P1CHUNK(7)
    const float zmax = fmaxf(fmaxf(zm0, zm1), fmaxf(zm2, zm3));

    // rescale exponent kc (zmax==0 -> log2=-inf -> kc=20)
    const float expo = __log2f(zmax) * plt;
    float kc = 0.f;
    if (expo < -20.f) {
      kc = fminf(fmaxf(ceilf((-15.f - expo) * inv_p), 0.f), 20.f);
    }
    const float kcl = kc * L2_10;      // log2(k)
    const float A   = p * kcl;         // exponent offset for w2

    // ---- pass 2 (dhdx fused; C2 scalar factors out of lv-weighted sum) ----
    float s0 = 0.f, s1 = 0.f, s2 = 0.f, s3 = 0.f;
    float ax = 0.f, ay = 0.f, az = 0.f;
    P2CHUNK(0) P2CHUNK(1) P2CHUNK(2) P2CHUNK(3)
    P2CHUNK(4) P2CHUNK(5) P2CHUNK(6) P2CHUNK(7)
    const float ssum = (s0 + s1) + (s2 + s3);

    float lh = LH_MIN;
    float C2 = 0.f;                    // dhdz_i = w2_i * C2
    if (ssum > 0.f) {
      lh = inv_p * __log2f(ssum);
      C2 = fexp2(-fmaf(pm1, lh, kcl));
    }

    const int pbase = bp * DD + d;
    out[O_POINTS + pbase * 3 + 0] = fmaf(C2, ax, mx);
    out[O_POINTS + pbase * 3 + 1] = fmaf(C2, ay, my);
    out[O_POINTS + pbase * 3 + 2] = fmaf(C2, az, mz);

    // direction_h row as one dwordx4 store (w = h/k)
    float4 dvh = make_float4(dx, dy, dz, fexp2(lh - kcl));
    ((float4*)(out + O_DIRH))[pbase] = dvh;
  }
}

extern "C" void kernel_launch(void* const* d_in, const int* in_sizes, int n_in,
                              void* d_out, int out_size, void* d_ws, size_t ws_size,
                              hipStream_t stream) {
  const float* vertices = (const float*)d_in[0];  // (8,64,32,3) f32
  const float* smooth   = (const float*)d_in[1];  // (8,64) f32
  float* out = (float*)d_out;

  // 4 direction-quarters x 512 bp = 2048 blocks = 8 blocks/CU
  spt_kernel<<<dim3(NBP, 4), 256, 0, stream>>>(vertices, smooth, out);
}

// Round 4
// 143.314 us; speedup vs baseline: 1.8379x; 1.8379x over previous
//
#include <hip/hip_runtime.h>
#include <math.h>

// Problem constants (B=8, P=64, V=32, N_TH1=30 -> D=1626)
#define NBP 512          // B*P
#define VV 32
#define DD 1626
#define DHALF 813        // directions per block (2 halves)

// Output layout (flat float32, concatenated in return order)
#define O_POINTS 0                         // (8,64*1626,3)  = 2497536
#define O_DIRH   2497536                   // (8,64,1626,4)  = 3330048
#define O_OVER   5827584                   // (8,64,1)       = 512
#define O_RETR   5828096                   // (8,64,1)       = 512
#define O_MEAN   5828608                   // (8,64,3)       = 1536
#define O_LOCAL  5830144                   // (8,64,32,3)    = 49152

#define L10_2 0.3010299956639812f    // log10(2)
#define L2_10 3.321928094887362f     // log2(10)
#define LH_MIN -66.43856189774725f   // log2(1e-20)

__device__ __forceinline__ float fexp2(float x) {
  return __builtin_amdgcn_exp2f(x);    // raw v_exp_f32
}

// inline direction via hardware v_sin/v_cos
__device__ __forceinline__ void make_dir_fast(int d, float& x, float& y, float& z) {
  if (d < 1624) {
    const int i1 = d / 58 + 1;        // 1..28
    const int i2 = d - (i1 - 1) * 58; // 0..57
    const float STEP = 0.10833078115826873f;        // pi/29
    const float th1 = -1.5707963267948966f + (float)i1 * STEP;
    const float th2 = -3.14159265358979323846f + (float)i2 * STEP;
    const float s1 = __sinf(th1);
    const float c1 = __cosf(th1);
    const float s2 = __sinf(th2);
    const float c2 = __cosf(th2);
    x = c1 * c2; y = c1 * s2; z = s1;
  } else if (d == 1624) {             // pole th1=-pi/2 (numpy f64->f32 values)
    x = -6.123234e-17f; y = -7.49880e-33f; z = -1.0f;
  } else {                            // pole th1=+pi/2
    x = -6.123234e-17f; y = -7.49880e-33f; z = 1.0f;
  }
}

// z-chunk: identical expression/order to all passing rounds
#define ZCH(X, Y, Z, DX, DY, DZ, z0, z1, z2, z3)                       \
  z0 = fmaxf(fmaf((X).x, DX, fmaf((Y).x, DY, (Z).x * DZ)), 0.f);       \
  z1 = fmaxf(fmaf((X).y, DX, fmaf((Y).y, DY, (Z).y * DZ)), 0.f);       \
  z2 = fmaxf(fmaf((X).z, DX, fmaf((Y).z, DY, (Z).z * DZ)), 0.f);       \
  z3 = fmaxf(fmaf((X).w, DX, fmaf((Y).w, DY, (Z).w * DZ)), 0.f);

// ---------------- single-direction body (round-2 proven numerics) ----------
__device__ __forceinline__ void process_one(
    int bp, int d, float mx, float my, float mz,
    float p, float inv_p, float pm1, float plt,
    const float4* lvx4, const float4* lvy4, const float4* lvz4,
    float* __restrict__ out)
{
  float dx, dy, dz;
  make_dir_fast(d, dx, dy, dz);

  float zm0 = 0.f, zm1 = 0.f, zm2 = 0.f, zm3 = 0.f;
#pragma unroll
  for (int j = 0; j < 8; ++j) {
    const float4 X = lvx4[j], Y = lvy4[j], Z = lvz4[j];
    float z0, z1, z2, z3; ZCH(X, Y, Z, dx, dy, dz, z0, z1, z2, z3)
    zm0 = fmaxf(zm0, z0); zm1 = fmaxf(zm1, z1);
    zm2 = fmaxf(zm2, z2); zm3 = fmaxf(zm3, z3);
  }
  const float zmax = fmaxf(fmaxf(zm0, zm1), fmaxf(zm2, zm3));

  const float expo = __log2f(zmax) * plt;
  float kc = 0.f;
  if (expo < -20.f) kc = fminf(fmaxf(ceilf((-15.f - expo) * inv_p), 0.f), 20.f);
  const float kcl = kc * L2_10;
  const float A   = p * kcl;

  float s0 = 0.f, s1 = 0.f, s2 = 0.f, s3 = 0.f;
  float ax = 0.f, ay = 0.f, az = 0.f;
#pragma unroll
  for (int j = 0; j < 8; ++j) {
    const float4 X = lvx4[j], Y = lvy4[j], Z = lvz4[j];
    float z0, z1, z2, z3; ZCH(X, Y, Z, dx, dy, dz, z0, z1, z2, z3)
    float w0 = fexp2(fmaf(pm1, __log2f(z0), A));
    float w1 = fexp2(fmaf(pm1, __log2f(z1), A));
    float w2 = fexp2(fmaf(pm1, __log2f(z2), A));
    float w3 = fexp2(fmaf(pm1, __log2f(z3), A));
    s0 += w0 * z0;  s1 += w1 * z1;
    s2 += w2 * z2;  s3 += w3 * z3;
    ax = fmaf(w0, X.x, fmaf(w1, X.y, fmaf(w2, X.z, fmaf(w3, X.w, ax))));
    ay = fmaf(w0, Y.x, fmaf(w1, Y.y, fmaf(w2, Y.z, fmaf(w3, Y.w, ay))));
    az = fmaf(w0, Z.x, fmaf(w1, Z.y, fmaf(w2, Z.z, fmaf(w3, Z.w, az))));
  }
  const float ssum = (s0 + s1) + (s2 + s3);

  float lh = LH_MIN, C2 = 0.f;
  if (ssum > 0.f) {
    lh = inv_p * __log2f(ssum);
    C2 = fexp2(-fmaf(pm1, lh, kcl));
  }

  const int pbase = bp * DD + d;
  out[O_POINTS + pbase * 3 + 0] = fmaf(C2, ax, mx);
  out[O_POINTS + pbase * 3 + 1] = fmaf(C2, ay, my);
  out[O_POINTS + pbase * 3 + 2] = fmaf(C2, az, mz);
  float4 dvh = make_float4(dx, dy, dz, fexp2(lh - kcl));
  ((float4*)(out + O_DIRH))[pbase] = dvh;
}

// ---------------- dual-direction body: shared LDS reads, 2x ILP ------------
__device__ __forceinline__ void process_two(
    int bp, int dA, int dB, float mx, float my, float mz,
    float p, float inv_p, float pm1, float plt,
    const float4* lvx4, const float4* lvy4, const float4* lvz4,
    float* __restrict__ out)
{
  float dxA, dyA, dzA, dxB, dyB, dzB;
  make_dir_fast(dA, dxA, dyA, dzA);
  make_dir_fast(dB, dxB, dyB, dzB);

  // ---- pass 1: zmax for both dirs, one LDS read per chunk ----
  float mA0 = 0.f, mA1 = 0.f, mA2 = 0.f, mA3 = 0.f;
  float mB0 = 0.f, mB1 = 0.f, mB2 = 0.f, mB3 = 0.f;
#pragma unroll
  for (int j = 0; j < 8; ++j) {
    const float4 X = lvx4[j], Y = lvy4[j], Z = lvz4[j];
    float a0, a1, a2, a3, b0, b1, b2, b3;
    ZCH(X, Y, Z, dxA, dyA, dzA, a0, a1, a2, a3)
    ZCH(X, Y, Z, dxB, dyB, dzB, b0, b1, b2, b3)
    mA0 = fmaxf(mA0, a0); mA1 = fmaxf(mA1, a1);
    mA2 = fmaxf(mA2, a2); mA3 = fmaxf(mA3, a3);
    mB0 = fmaxf(mB0, b0); mB1 = fmaxf(mB1, b1);
    mB2 = fmaxf(mB2, b2); mB3 = fmaxf(mB3, b3);
  }
  const float zmaxA = fmaxf(fmaxf(mA0, mA1), fmaxf(mA2, mA3));
  const float zmaxB = fmaxf(fmaxf(mB0, mB1), fmaxf(mB2, mB3));

  const float expoA = __log2f(zmaxA) * plt;
  float kcA = 0.f;
  if (expoA < -20.f) kcA = fminf(fmaxf(ceilf((-15.f - expoA) * inv_p), 0.f), 20.f);
  const float kclA = kcA * L2_10;
  const float AA   = p * kclA;

  const float expoB = __log2f(zmaxB) * plt;
  float kcB = 0.f;
  if (expoB < -20.f) kcB = fminf(fmaxf(ceilf((-15.f - expoB) * inv_p), 0.f), 20.f);
  const float kclB = kcB * L2_10;
  const float AB   = p * kclB;

  // ---- pass 2 for both dirs, one LDS read per chunk ----
  float sA0 = 0.f, sA1 = 0.f, sA2 = 0.f, sA3 = 0.f;
  float sB0 = 0.f, sB1 = 0.f, sB2 = 0.f, sB3 = 0.f;
  float axA = 0.f, ayA = 0.f, azA = 0.f;
  float axB = 0.f, ayB = 0.f, azB = 0.f;
#pragma unroll
  for (int j = 0; j < 8; ++j) {
    const float4 X = lvx4[j], Y = lvy4[j], Z = lvz4[j];
    float a0, a1, a2, a3, b0, b1, b2, b3;
    ZCH(X, Y, Z, dxA, dyA, dzA, a0, a1, a2, a3)
    ZCH(X, Y, Z, dxB, dyB, dzB, b0, b1, b2, b3)
    float u0 = fexp2(fmaf(pm1, __log2f(a0), AA));
    float u1 = fexp2(fmaf(pm1, __log2f(a1), AA));
    float u2 = fexp2(fmaf(pm1, __log2f(a2), AA));
    float u3 = fexp2(fmaf(pm1, __log2f(a3), AA));
    float v0 = fexp2(fmaf(pm1, __log2f(b0), AB));
    float v1 = fexp2(fmaf(pm1, __log2f(b1), AB));
    float v2 = fexp2(fmaf(pm1, __log2f(b2), AB));
    float v3 = fexp2(fmaf(pm1, __log2f(b3), AB));
    sA0 += u0 * a0;  sA1 += u1 * a1;
    sA2 += u2 * a2;  sA3 += u3 * a3;
    sB0 += v0 * b0;  sB1 += v1 * b1;
    sB2 += v2 * b2;  sB3 += v3 * b3;
    axA = fmaf(u0, X.x, fmaf(u1, X.y, fmaf(u2, X.z, fmaf(u3, X.w, axA))));
    ayA = fmaf(u0, Y.x, fmaf(u1, Y.y, fmaf(u2, Y.z, fmaf(u3, Y.w, ayA))));
    azA = fmaf(u0, Z.x, fmaf(u1, Z.y, fmaf(u2, Z.z, fmaf(u3, Z.w, azA))));
    axB = fmaf(v0, X.x, fmaf(v1, X.y, fmaf(v2, X.z, fmaf(v3, X.w, axB))));
    ayB = fmaf(v0, Y.x, fmaf(v1, Y.y, fmaf(v2, Y.z, fmaf(v3, Y.w, ayB))));
    azB = fmaf(v0, Z.x, fmaf(v1, Z.y, fmaf(v2, Z.z, fmaf(v3, Z.w, azB))));
  }
  const float ssumA = (sA0 + sA1) + (sA2 + sA3);
  const float ssumB = (sB0 + sB1) + (sB2 + sB3);

  float lhA = LH_MIN, C2A = 0.f;
  if (ssumA > 0.f) {
    lhA = inv_p * __log2f(ssumA);
    C2A = fexp2(-fmaf(pm1, lhA, kclA));
  }
  float lhB = LH_MIN, C2B = 0.f;
  if (ssumB > 0.f) {
    lhB = inv_p * __log2f(ssumB);
    C2B = fexp2(-fmaf(pm1, lhB, kclB));
  }

  const int pbA = bp * DD + dA;
  const int pbB = bp * DD + dB;
  out[O_POINTS + pbA * 3 + 0] = fmaf(C2A, axA, mx);
  out[O_POINTS + pbA * 3 + 1] = fmaf(C2A, ayA, my);
  out[O_POINTS + pbA * 3 + 2] = fmaf(C2A, azA, mz);
  out[O_POINTS + pbB * 3 + 0] = fmaf(C2B, axB, mx);
  out[O_POINTS + pbB * 3 + 1] = fmaf(C2B, ayB, my);
  out[O_POINTS + pbB * 3 + 2] = fmaf(C2B, azB, mz);
  float4 dvhA = make_float4(dxA, dyA, dzA, fexp2(lhA - kclA));
  float4 dvhB = make_float4(dxB, dyB, dzB, fexp2(lhB - kclB));
  ((float4*)(out + O_DIRH))[pbA] = dvhA;
  ((float4*)(out + O_DIRH))[pbB] = dvhB;
}

// Round-0 grid (512,2); cap 128 VGPR (dual-body demand ~90) -> 4 waves/SIMD
__global__ __launch_bounds__(256, 4) void spt_kernel(
    const float* __restrict__ vertices,
    const float* __restrict__ smooth,
    float* __restrict__ out)
{
  const int bp   = blockIdx.x;   // 0..511
  const int half = blockIdx.y;   // 0..1
  const int tid  = threadIdx.x;

  __shared__ __align__(16) float slvx[VV];
  __shared__ __align__(16) float slvy[VV];
  __shared__ __align__(16) float slvz[VV];

  const int dbase = half * DHALF;

  // ---- wave-redundant mean via shuffle; lv -> LDS; ONE barrier ----
  const int v = tid & 31;
  const float* vp = vertices + bp * (VV * 3) + v * 3;
  const float vx = vp[0], vy = vp[1], vz = vp[2];
  float sx = vx, sy = vy, sz = vz;
#pragma unroll
  for (int m = 16; m >= 1; m >>= 1) {
    sx += __shfl_xor(sx, m);
    sy += __shfl_xor(sy, m);
    sz += __shfl_xor(sz, m);
  }
  const float mx = sx * (1.0f / 32.0f);
  const float my = sy * (1.0f / 32.0f);
  const float mz = sz * (1.0f / 32.0f);
  if (tid < VV) {
    slvx[tid] = vx - mx;
    slvy[tid] = vy - my;
    slvz[tid] = vz - mz;
  }
  __syncthreads();

  // ---- side outputs (once, by half 1) ----
  if (half == 1) {
    if (tid < VV * 3) {
      const int vv = tid / 3, c = tid - vv * 3;
      const float val = (c == 0) ? slvx[vv] : ((c == 1) ? slvy[vv] : slvz[vv]);
      out[O_LOCAL + bp * (VV * 3) + tid] = val;
    }
    if (tid == 96) {
      out[O_MEAN + bp * 3 + 0] = mx;
      out[O_MEAN + bp * 3 + 1] = my;
      out[O_MEAN + bp * 3 + 2] = mz;
      out[O_OVER + bp] = 0.f;
      out[O_RETR + bp] = 0.f;
    }
  }

  const float p     = smooth[bp];
  const float inv_p = 1.0f / p;
  const float pm1   = p - 1.0f;
  const float plt   = p * L10_2;

  const float4* lvx4 = (const float4*)slvx;
  const float4* lvy4 = (const float4*)slvy;
  const float4* lvz4 = (const float4*)slvz;

  // dirs (tid, tid+256) as a dual-ILP pair sharing LDS reads
  process_two(bp, dbase + tid, dbase + 256 + tid, mx, my, mz,
              p, inv_p, pm1, plt, lvx4, lvy4, lvz4, out);
  // dir 512+tid single; tail 768+tid only on first wave (45 threads)
  process_one(bp, dbase + 512 + tid, mx, my, mz,
              p, inv_p, pm1, plt, lvx4, lvy4, lvz4, out);
  if (tid < DHALF - 768)
    process_one(bp, dbase + 768 + tid, mx, my, mz,
                p, inv_p, pm1, plt, lvx4, lvy4, lvz4, out);
}

extern "C" void kernel_launch(void* const* d_in, const int* in_sizes, int n_in,
                              void* d_out, int out_size, void* d_ws, size_t ws_size,
                              hipStream_t stream) {
  const float* vertices = (const float*)d_in[0];  // (8,64,32,3) f32
  const float* smooth   = (const float*)d_in[1];  // (8,64) f32
  float* out = (float*)d_out;

  spt_kernel<<<dim3(NBP, 2), 256, 0, stream>>>(vertices, smooth, out);
}

// Round 6
// 80.538 us; speedup vs baseline: 3.2704x; 1.7795x over previous
//
#include <hip/hip_runtime.h>
#include <math.h>

// Problem constants (B=8, P=64, V=32, N_TH1=30 -> D=1626)
#define NBP 512          // B*P
#define VV 32
#define DD 1626
#define DHALF 813        // directions per block (2 halves)

// Output layout (flat float32, concatenated in return order)
#define O_POINTS 0                         // (8,64*1626,3)  = 2497536
#define O_DIRH   2497536                   // (8,64,1626,4)  = 3330048
#define O_OVER   5827584                   // (8,64,1)       = 512
#define O_RETR   5828096                   // (8,64,1)       = 512
#define O_MEAN   5828608                   // (8,64,3)       = 1536
#define O_LOCAL  5830144                   // (8,64,32,3)    = 49152

#define L10_2 0.3010299956639812f    // log10(2)
#define L2_10 3.321928094887362f     // log2(10)
#define LH_MIN -66.43856189774725f   // log2(1e-20)

__device__ __forceinline__ float fexp2(float x) {
  return __builtin_amdgcn_exp2f(x);    // raw v_exp_f32
}

// inline direction via hardware v_sin/v_cos
__device__ __forceinline__ void make_dir_fast(int d, float& x, float& y, float& z) {
  if (d < 1624) {
    const int i1 = d / 58 + 1;        // 1..28
    const int i2 = d - (i1 - 1) * 58; // 0..57
    const float STEP = 0.10833078115826873f;        // pi/29
    const float th1 = -1.5707963267948966f + (float)i1 * STEP;
    const float th2 = -3.14159265358979323846f + (float)i2 * STEP;
    const float s1 = __sinf(th1);
    const float c1 = __cosf(th1);
    const float s2 = __sinf(th2);
    const float c2 = __cosf(th2);
    x = c1 * c2; y = c1 * s2; z = s1;
  } else if (d == 1624) {             // pole th1=-pi/2 (numpy f64->f32 values)
    x = -6.123234e-17f; y = -7.49880e-33f; z = -1.0f;
  } else {                            // pole th1=+pi/2
    x = -6.123234e-17f; y = -7.49880e-33f; z = 1.0f;
  }
}

// z-chunk: identical expression/order to all passing rounds
#define ZCH(X, Y, Z, DX, DY, DZ, z0, z1, z2, z3)                       \
  z0 = fmaxf(fmaf((X).x, DX, fmaf((Y).x, DY, (Z).x * DZ)), 0.f);       \
  z1 = fmaxf(fmaf((X).y, DX, fmaf((Y).y, DY, (Z).y * DZ)), 0.f);       \
  z2 = fmaxf(fmaf((X).z, DX, fmaf((Y).z, DY, (Z).z * DZ)), 0.f);       \
  z3 = fmaxf(fmaf((X).w, DX, fmaf((Y).w, DY, (Z).w * DZ)), 0.f);

// ---------------- single-direction body (round-2 proven numerics) ----------
__device__ __forceinline__ void process_one(
    int bp, int d, float mx, float my, float mz,
    float p, float inv_p, float pm1, float plt,
    const float4* lvx4, const float4* lvy4, const float4* lvz4,
    float* __restrict__ out)
{
  float dx, dy, dz;
  make_dir_fast(d, dx, dy, dz);

  float zm0 = 0.f, zm1 = 0.f, zm2 = 0.f, zm3 = 0.f;
#pragma unroll
  for (int j = 0; j < 8; ++j) {
    const float4 X = lvx4[j], Y = lvy4[j], Z = lvz4[j];
    float z0, z1, z2, z3; ZCH(X, Y, Z, dx, dy, dz, z0, z1, z2, z3)
    zm0 = fmaxf(zm0, z0); zm1 = fmaxf(zm1, z1);
    zm2 = fmaxf(zm2, z2); zm3 = fmaxf(zm3, z3);
  }
  const float zmax = fmaxf(fmaxf(zm0, zm1), fmaxf(zm2, zm3));

  const float expo = __log2f(zmax) * plt;
  float kc = 0.f;
  if (expo < -20.f) kc = fminf(fmaxf(ceilf((-15.f - expo) * inv_p), 0.f), 20.f);
  const float kcl = kc * L2_10;
  const float A   = p * kcl;

  float s0 = 0.f, s1 = 0.f, s2 = 0.f, s3 = 0.f;
  float ax = 0.f, ay = 0.f, az = 0.f;
#pragma unroll
  for (int j = 0; j < 8; ++j) {
    const float4 X = lvx4[j], Y = lvy4[j], Z = lvz4[j];
    float z0, z1, z2, z3; ZCH(X, Y, Z, dx, dy, dz, z0, z1, z2, z3)
    float w0 = fexp2(fmaf(pm1, __log2f(z0), A));
    float w1 = fexp2(fmaf(pm1, __log2f(z1), A));
    float w2 = fexp2(fmaf(pm1, __log2f(z2), A));
    float w3 = fexp2(fmaf(pm1, __log2f(z3), A));
    s0 += w0 * z0;  s1 += w1 * z1;
    s2 += w2 * z2;  s3 += w3 * z3;
    ax = fmaf(w0, X.x, fmaf(w1, X.y, fmaf(w2, X.z, fmaf(w3, X.w, ax))));
    ay = fmaf(w0, Y.x, fmaf(w1, Y.y, fmaf(w2, Y.z, fmaf(w3, Y.w, ay))));
    az = fmaf(w0, Z.x, fmaf(w1, Z.y, fmaf(w2, Z.z, fmaf(w3, Z.w, az))));
  }
  const float ssum = (s0 + s1) + (s2 + s3);

  float lh = LH_MIN, C2 = 0.f;
  if (ssum > 0.f) {
    lh = inv_p * __log2f(ssum);
    C2 = fexp2(-fmaf(pm1, lh, kcl));
  }

  const int pbase = bp * DD + d;
  out[O_POINTS + pbase * 3 + 0] = fmaf(C2, ax, mx);
  out[O_POINTS + pbase * 3 + 1] = fmaf(C2, ay, my);
  out[O_POINTS + pbase * 3 + 2] = fmaf(C2, az, mz);
  float4 dvh = make_float4(dx, dy, dz, fexp2(lh - kcl));
  ((float4*)(out + O_DIRH))[pbase] = dvh;
}

// ---------------- dual-direction body: shared LDS reads, 2x ILP ------------
__device__ __forceinline__ void process_two(
    int bp, int dA, int dB, float mx, float my, float mz,
    float p, float inv_p, float pm1, float plt,
    const float4* lvx4, const float4* lvy4, const float4* lvz4,
    float* __restrict__ out)
{
  float dxA, dyA, dzA, dxB, dyB, dzB;
  make_dir_fast(dA, dxA, dyA, dzA);
  make_dir_fast(dB, dxB, dyB, dzB);

  // ---- pass 1: zmax for both dirs, one LDS read per chunk ----
  float mA0 = 0.f, mA1 = 0.f, mA2 = 0.f, mA3 = 0.f;
  float mB0 = 0.f, mB1 = 0.f, mB2 = 0.f, mB3 = 0.f;
#pragma unroll
  for (int j = 0; j < 8; ++j) {
    const float4 X = lvx4[j], Y = lvy4[j], Z = lvz4[j];
    float a0, a1, a2, a3, b0, b1, b2, b3;
    ZCH(X, Y, Z, dxA, dyA, dzA, a0, a1, a2, a3)
    ZCH(X, Y, Z, dxB, dyB, dzB, b0, b1, b2, b3)
    mA0 = fmaxf(mA0, a0); mA1 = fmaxf(mA1, a1);
    mA2 = fmaxf(mA2, a2); mA3 = fmaxf(mA3, a3);
    mB0 = fmaxf(mB0, b0); mB1 = fmaxf(mB1, b1);
    mB2 = fmaxf(mB2, b2); mB3 = fmaxf(mB3, b3);
  }
  const float zmaxA = fmaxf(fmaxf(mA0, mA1), fmaxf(mA2, mA3));
  const float zmaxB = fmaxf(fmaxf(mB0, mB1), fmaxf(mB2, mB3));

  const float expoA = __log2f(zmaxA) * plt;
  float kcA = 0.f;
  if (expoA < -20.f) kcA = fminf(fmaxf(ceilf((-15.f - expoA) * inv_p), 0.f), 20.f);
  const float kclA = kcA * L2_10;
  const float AA   = p * kclA;

  const float expoB = __log2f(zmaxB) * plt;
  float kcB = 0.f;
  if (expoB < -20.f) kcB = fminf(fmaxf(ceilf((-15.f - expoB) * inv_p), 0.f), 20.f);
  const float kclB = kcB * L2_10;
  const float AB   = p * kclB;

  // ---- pass 2 for both dirs, one LDS read per chunk ----
  float sA0 = 0.f, sA1 = 0.f, sA2 = 0.f, sA3 = 0.f;
  float sB0 = 0.f, sB1 = 0.f, sB2 = 0.f, sB3 = 0.f;
  float axA = 0.f, ayA = 0.f, azA = 0.f;
  float axB = 0.f, ayB = 0.f, azB = 0.f;
#pragma unroll
  for (int j = 0; j < 8; ++j) {
    const float4 X = lvx4[j], Y = lvy4[j], Z = lvz4[j];
    float a0, a1, a2, a3, b0, b1, b2, b3;
    ZCH(X, Y, Z, dxA, dyA, dzA, a0, a1, a2, a3)
    ZCH(X, Y, Z, dxB, dyB, dzB, b0, b1, b2, b3)
    float u0 = fexp2(fmaf(pm1, __log2f(a0), AA));
    float u1 = fexp2(fmaf(pm1, __log2f(a1), AA));
    float u2 = fexp2(fmaf(pm1, __log2f(a2), AA));
    float u3 = fexp2(fmaf(pm1, __log2f(a3), AA));
    float v0 = fexp2(fmaf(pm1, __log2f(b0), AB));
    float v1 = fexp2(fmaf(pm1, __log2f(b1), AB));
    float v2 = fexp2(fmaf(pm1, __log2f(b2), AB));
    float v3 = fexp2(fmaf(pm1, __log2f(b3), AB));
    sA0 += u0 * a0;  sA1 += u1 * a1;
    sA2 += u2 * a2;  sA3 += u3 * a3;
    sB0 += v0 * b0;  sB1 += v1 * b1;
    sB2 += v2 * b2;  sB3 += v3 * b3;
    axA = fmaf(u0, X.x, fmaf(u1, X.y, fmaf(u2, X.z, fmaf(u3, X.w, axA))));
    ayA = fmaf(u0, Y.x, fmaf(u1, Y.y, fmaf(u2, Y.z, fmaf(u3, Y.w, ayA))));
    azA = fmaf(u0, Z.x, fmaf(u1, Z.y, fmaf(u2, Z.z, fmaf(u3, Z.w, azA))));
    axB = fmaf(v0, X.x, fmaf(v1, X.y, fmaf(v2, X.z, fmaf(v3, X.w, axB))));
    ayB = fmaf(v0, Y.x, fmaf(v1, Y.y, fmaf(v2, Y.z, fmaf(v3, Y.w, ayB))));
    azB = fmaf(v0, Z.x, fmaf(v1, Z.y, fmaf(v2, Z.z, fmaf(v3, Z.w, azB))));
  }
  const float ssumA = (sA0 + sA1) + (sA2 + sA3);
  const float ssumB = (sB0 + sB1) + (sB2 + sB3);

  float lhA = LH_MIN, C2A = 0.f;
  if (ssumA > 0.f) {
    lhA = inv_p * __log2f(ssumA);
    C2A = fexp2(-fmaf(pm1, lhA, kclA));
  }
  float lhB = LH_MIN, C2B = 0.f;
  if (ssumB > 0.f) {
    lhB = inv_p * __log2f(ssumB);
    C2B = fexp2(-fmaf(pm1, lhB, kclB));
  }

  const int pbA = bp * DD + dA;
  const int pbB = bp * DD + dB;
  out[O_POINTS + pbA * 3 + 0] = fmaf(C2A, axA, mx);
  out[O_POINTS + pbA * 3 + 1] = fmaf(C2A, ayA, my);
  out[O_POINTS + pbA * 3 + 2] = fmaf(C2A, azA, mz);
  out[O_POINTS + pbB * 3 + 0] = fmaf(C2B, axB, mx);
  out[O_POINTS + pbB * 3 + 1] = fmaf(C2B, ayB, my);
  out[O_POINTS + pbB * 3 + 2] = fmaf(C2B, azB, mz);
  float4 dvhA = make_float4(dxA, dyA, dzA, fexp2(lhA - kclA));
  float4 dvhB = make_float4(dxB, dyB, dzB, fexp2(lhB - kclB));
  ((float4*)(out + O_DIRH))[pbA] = dvhA;
  ((float4*)(out + O_DIRH))[pbB] = dvhB;
}

// NO min-waves constraint: every capped config (168/128/64) spilled; round 0
// (uncapped) was the only spill-free kernel. Let the allocator take ~160-200.
__global__ __launch_bounds__(256) void spt_kernel(
    const float* __restrict__ vertices,
    const float* __restrict__ smooth,
    float* __restrict__ out)
{
  const int bp   = blockIdx.x;   // 0..511
  const int half = blockIdx.y;   // 0..1
  const int tid  = threadIdx.x;

  __shared__ __align__(16) float slvx[VV];
  __shared__ __align__(16) float slvy[VV];
  __shared__ __align__(16) float slvz[VV];

  const int dbase = half * DHALF;

  // ---- wave-redundant mean via shuffle; lv -> LDS; ONE barrier ----
  const int v = tid & 31;
  const float* vp = vertices + bp * (VV * 3) + v * 3;
  const float vx = vp[0], vy = vp[1], vz = vp[2];
  float sx = vx, sy = vy, sz = vz;
#pragma unroll
  for (int m = 16; m >= 1; m >>= 1) {
    sx += __shfl_xor(sx, m);
    sy += __shfl_xor(sy, m);
    sz += __shfl_xor(sz, m);
  }
  const float mx = sx * (1.0f / 32.0f);
  const float my = sy * (1.0f / 32.0f);
  const float mz = sz * (1.0f / 32.0f);
  if (tid < VV) {
    slvx[tid] = vx - mx;
    slvy[tid] = vy - my;
    slvz[tid] = vz - mz;
  }
  __syncthreads();

  // ---- side outputs (once, by half 1) ----
  if (half == 1) {
    if (tid < VV * 3) {
      const int vv = tid / 3, c = tid - vv * 3;
      const float val = (c == 0) ? slvx[vv] : ((c == 1) ? slvy[vv] : slvz[vv]);
      out[O_LOCAL + bp * (VV * 3) + tid] = val;
    }
    if (tid == 96) {
      out[O_MEAN + bp * 3 + 0] = mx;
      out[O_MEAN + bp * 3 + 1] = my;
      out[O_MEAN + bp * 3 + 2] = mz;
      out[O_OVER + bp] = 0.f;
      out[O_RETR + bp] = 0.f;
    }
  }

  const float p     = smooth[bp];
  const float inv_p = 1.0f / p;
  const float pm1   = p - 1.0f;
  const float plt   = p * L10_2;

  const float4* lvx4 = (const float4*)slvx;
  const float4* lvy4 = (const float4*)slvy;
  const float4* lvz4 = (const float4*)slvz;

  // dirs (tid, tid+256) as a dual-ILP pair sharing LDS reads
  process_two(bp, dbase + tid, dbase + 256 + tid, mx, my, mz,
              p, inv_p, pm1, plt, lvx4, lvy4, lvz4, out);
  // dir 512+tid single; tail 768+tid only on first wave (45 threads)
  process_one(bp, dbase + 512 + tid, mx, my, mz,
              p, inv_p, pm1, plt, lvx4, lvy4, lvz4, out);
  if (tid < DHALF - 768)
    process_one(bp, dbase + 768 + tid, mx, my, mz,
                p, inv_p, pm1, plt, lvx4, lvy4, lvz4, out);
}

extern "C" void kernel_launch(void* const* d_in, const int* in_sizes, int n_in,
                              void* d_out, int out_size, void* d_ws, size_t ws_size,
                              hipStream_t stream) {
  const float* vertices = (const float*)d_in[0];  // (8,64,32,3) f32
  const float* smooth   = (const float*)d_in[1];  // (8,64) f32
  float* out = (float*)d_out;

  spt_kernel<<<dim3(NBP, 2), 256, 0, stream>>>(vertices, smooth, out);
}

// Round 7
// 75.267 us; speedup vs baseline: 3.4994x; 1.0700x over previous
//
#include <hip/hip_runtime.h>
#include <math.h>

// Problem constants (B=8, P=64, V=32, N_TH1=30 -> D=1626)
#define NBP 512          // B*P
#define VV 32
#define DD 1626
#define DHALF 813        // directions per block (2 halves)

// Output layout (flat float32, concatenated in return order)
#define O_POINTS 0                         // (8,64*1626,3)  = 2497536
#define O_DIRH   2497536                   // (8,64,1626,4)  = 3330048
#define O_OVER   5827584                   // (8,64,1)       = 512
#define O_RETR   5828096                   // (8,64,1)       = 512
#define O_MEAN   5828608                   // (8,64,3)       = 1536
#define O_LOCAL  5830144                   // (8,64,32,3)    = 49152

#define L10_2 0.3010299956639812f    // log10(2)
#define L2_10 3.321928094887362f     // log2(10)
#define LH_MIN -66.43856189774725f   // log2(1e-20)

__device__ __forceinline__ float fexp2(float x) {
  return __builtin_amdgcn_exp2f(x);    // raw v_exp_f32
}

// inline direction via hardware v_sin/v_cos
__device__ __forceinline__ void make_dir_fast(int d, float& x, float& y, float& z) {
  if (d < 1624) {
    const int i1 = d / 58 + 1;        // 1..28
    const int i2 = d - (i1 - 1) * 58; // 0..57
    const float STEP = 0.10833078115826873f;        // pi/29
    const float th1 = -1.5707963267948966f + (float)i1 * STEP;
    const float th2 = -3.14159265358979323846f + (float)i2 * STEP;
    const float s1 = __sinf(th1);
    const float c1 = __cosf(th1);
    const float s2 = __sinf(th2);
    const float c2 = __cosf(th2);
    x = c1 * c2; y = c1 * s2; z = s1;
  } else if (d == 1624) {             // pole th1=-pi/2 (numpy f64->f32 values)
    x = -6.123234e-17f; y = -7.49880e-33f; z = -1.0f;
  } else {                            // pole th1=+pi/2
    x = -6.123234e-17f; y = -7.49880e-33f; z = 1.0f;
  }
}

// SGPR broadcast: v_readlane_b32 -> scalar register, bit-exact
#define RL(x, i) __uint_as_float(__builtin_amdgcn_readlane(__float_as_uint(x), (i)))

// one 4-vertex chunk of local_v into named scalars (SGPR-resident)
#define DECL_CHUNK(b)                                                       \
  const float cx_##b##_0 = RL(lvx, 4*b+0), cx_##b##_1 = RL(lvx, 4*b+1),     \
              cx_##b##_2 = RL(lvx, 4*b+2), cx_##b##_3 = RL(lvx, 4*b+3);     \
  const float cy_##b##_0 = RL(lvy, 4*b+0), cy_##b##_1 = RL(lvy, 4*b+1),     \
              cy_##b##_2 = RL(lvy, 4*b+2), cy_##b##_3 = RL(lvy, 4*b+3);     \
  const float cz_##b##_0 = RL(lvz, 4*b+0), cz_##b##_1 = RL(lvz, 4*b+1),     \
              cz_##b##_2 = RL(lvz, 4*b+2), cz_##b##_3 = RL(lvz, 4*b+3);

// pass-1 chunk: z from SGPR operands (1 SGPR/instr - within ISA limit), max
#define P1CH(b) {                                                           \
  float z0 = fmaxf(fmaf(cx_##b##_0, dx, fmaf(cy_##b##_0, dy, cz_##b##_0 * dz)), 0.f); \
  float z1 = fmaxf(fmaf(cx_##b##_1, dx, fmaf(cy_##b##_1, dy, cz_##b##_1 * dz)), 0.f); \
  float z2 = fmaxf(fmaf(cx_##b##_2, dx, fmaf(cy_##b##_2, dy, cz_##b##_2 * dz)), 0.f); \
  float z3 = fmaxf(fmaf(cx_##b##_3, dx, fmaf(cy_##b##_3, dy, cz_##b##_3 * dz)), 0.f); \
  zm0 = fmaxf(zm0, z0); zm1 = fmaxf(zm1, z1);                               \
  zm2 = fmaxf(zm2, z2); zm3 = fmaxf(zm3, z3); }

// pass-2 chunk (proven fused numerics): w2=2^(pm1*log2(z)+A); s+=w2*z; a+=w2*lv
#define P2CH(b) {                                                           \
  float z0 = fmaxf(fmaf(cx_##b##_0, dx, fmaf(cy_##b##_0, dy, cz_##b##_0 * dz)), 0.f); \
  float z1 = fmaxf(fmaf(cx_##b##_1, dx, fmaf(cy_##b##_1, dy, cz_##b##_1 * dz)), 0.f); \
  float z2 = fmaxf(fmaf(cx_##b##_2, dx, fmaf(cy_##b##_2, dy, cz_##b##_2 * dz)), 0.f); \
  float z3 = fmaxf(fmaf(cx_##b##_3, dx, fmaf(cy_##b##_3, dy, cz_##b##_3 * dz)), 0.f); \
  float w0 = fexp2(fmaf(pm1, __log2f(z0), A));                              \
  float w1 = fexp2(fmaf(pm1, __log2f(z1), A));                              \
  float w2 = fexp2(fmaf(pm1, __log2f(z2), A));                              \
  float w3 = fexp2(fmaf(pm1, __log2f(z3), A));                              \
  s0 += w0 * z0;  s1 += w1 * z1;                                            \
  s2 += w2 * z2;  s3 += w3 * z3;                                            \
  ax = fmaf(w0, cx_##b##_0, fmaf(w1, cx_##b##_1, fmaf(w2, cx_##b##_2, fmaf(w3, cx_##b##_3, ax)))); \
  ay = fmaf(w0, cy_##b##_0, fmaf(w1, cy_##b##_1, fmaf(w2, cy_##b##_2, fmaf(w3, cy_##b##_3, ay)))); \
  az = fmaf(w0, cz_##b##_0, fmaf(w1, cz_##b##_1, fmaf(w2, cz_##b##_2, fmaf(w3, cz_##b##_3, az)))); }

// full per-direction body (macro, not lambda: no capture semantics, no arrays)
#define PROCESS(IDX) do {                                                   \
  const int d = dbase + (IDX);                                              \
  float dx, dy, dz;                                                         \
  make_dir_fast(d, dx, dy, dz);                                             \
  float zm0 = 0.f, zm1 = 0.f, zm2 = 0.f, zm3 = 0.f;                         \
  P1CH(0) P1CH(1) P1CH(2) P1CH(3) P1CH(4) P1CH(5) P1CH(6) P1CH(7)           \
  const float zmax = fmaxf(fmaxf(zm0, zm1), fmaxf(zm2, zm3));               \
  const float expo = __log2f(zmax) * plt;                                   \
  float kc = 0.f;                                                           \
  if (expo < -20.f) kc = fminf(fmaxf(ceilf((-15.f - expo) * inv_p), 0.f), 20.f); \
  const float kcl = kc * L2_10;                                             \
  const float A   = p * kcl;                                                \
  float s0 = 0.f, s1 = 0.f, s2 = 0.f, s3 = 0.f;                             \
  float ax = 0.f, ay = 0.f, az = 0.f;                                       \
  P2CH(0) P2CH(1) P2CH(2) P2CH(3) P2CH(4) P2CH(5) P2CH(6) P2CH(7)           \
  const float ssum = (s0 + s1) + (s2 + s3);                                 \
  float lh = LH_MIN, C2 = 0.f;                                              \
  if (ssum > 0.f) {                                                         \
    lh = inv_p * __log2f(ssum);                                             \
    C2 = fexp2(-fmaf(pm1, lh, kcl));                                        \
  }                                                                         \
  const int pbase = bp * DD + d;                                            \
  out[O_POINTS + pbase * 3 + 0] = fmaf(C2, ax, mx);                         \
  out[O_POINTS + pbase * 3 + 1] = fmaf(C2, ay, my);                         \
  out[O_POINTS + pbase * 3 + 2] = fmaf(C2, az, mz);                         \
  float4 dvh = make_float4(dx, dy, dz, fexp2(lh - kcl));                    \
  ((float4*)(out + O_DIRH))[pbase] = dvh;                                   \
} while (0)

// No LDS, no barriers, low VGPR demand; uncapped allocator (capped = spills).
__global__ __launch_bounds__(256) void spt_kernel(
    const float* __restrict__ vertices,
    const float* __restrict__ smooth,
    float* __restrict__ out)
{
  const int bp   = blockIdx.x;   // 0..511
  const int half = blockIdx.y;   // 0..1
  const int tid  = threadIdx.x;

  const int dbase = half * DHALF;

  // ---- wave-redundant mean via shuffle (each wave holds all 32 verts
  //      TWICE: lanes 0-31 and 32-63, since v = tid&31) ----
  const int v = tid & 31;
  const float* vp = vertices + bp * (VV * 3) + v * 3;
  const float vx = vp[0], vy = vp[1], vz = vp[2];
  float sx = vx, sy = vy, sz = vz;
#pragma unroll
  for (int m = 16; m >= 1; m >>= 1) {
    sx += __shfl_xor(sx, m);
    sy += __shfl_xor(sy, m);
    sz += __shfl_xor(sz, m);
  }
  const float mx = sx * (1.0f / 32.0f);
  const float my = sy * (1.0f / 32.0f);
  const float mz = sz * (1.0f / 32.0f);

  // per-lane local_v (lane i of each wave holds vertex i&31)
  const float lvx = vx - mx;
  const float lvy = vy - my;
  const float lvz = vz - mz;

  // ---- broadcast all 96 local_v scalars into SGPRs (bit-exact readlane;
  //      replaces LDS tile: zero ds_read / lgkmcnt in the main loop) ----
  DECL_CHUNK(0) DECL_CHUNK(1) DECL_CHUNK(2) DECL_CHUNK(3)
  DECL_CHUNK(4) DECL_CHUNK(5) DECL_CHUNK(6) DECL_CHUNK(7)

  // ---- side outputs (once, by half 1) ----
  if (half == 1) {
    if (tid < VV) {
      out[O_LOCAL + bp * (VV * 3) + tid * 3 + 0] = lvx;
      out[O_LOCAL + bp * (VV * 3) + tid * 3 + 1] = lvy;
      out[O_LOCAL + bp * (VV * 3) + tid * 3 + 2] = lvz;
    }
    if (tid == 96) {
      out[O_MEAN + bp * 3 + 0] = mx;
      out[O_MEAN + bp * 3 + 1] = my;
      out[O_MEAN + bp * 3 + 2] = mz;
      out[O_OVER + bp] = 0.f;
      out[O_RETR + bp] = 0.f;
    }
  }

  const float p     = smooth[bp];
  const float inv_p = 1.0f / p;
  const float pm1   = p - 1.0f;
  const float plt   = p * L10_2;

  PROCESS(tid);
  PROCESS(256 + tid);
  PROCESS(512 + tid);
  if (tid < DHALF - 768) PROCESS(768 + tid);   // 45 threads
}

extern "C" void kernel_launch(void* const* d_in, const int* in_sizes, int n_in,
                              void* d_out, int out_size, void* d_ws, size_t ws_size,
                              hipStream_t stream) {
  const float* vertices = (const float*)d_in[0];  // (8,64,32,3) f32
  const float* smooth   = (const float*)d_in[1];  // (8,64) f32
  float* out = (float*)d_out;

  spt_kernel<<<dim3(NBP, 2), 256, 0, stream>>>(vertices, smooth, out);
}